// Round 3
// baseline (118.717 us; speedup 1.0000x reference)
//
#include <hip/hip_runtime.h>

// PureAEVComputer radial AEV on MI355X — R3: species-sorted neighbor lists +
// even/odd exp-ratio trick + small accumulators for occupancy.
//
// Kernel 1 (16 blocks): counting-sort each batch's atoms by species into d_ws
//   as float4{x,y,z,s}; each species segment padded to a multiple of 64 with
//   sentinel coords (2e4) so the main loop needs no tail masking (d>5.2 -> fc=0).
// Kernel 2 (2048 blocks, 4 waves = 4 atoms each): per species segment, lanes
//   sweep 64-neighbor chunks accumulating acc[8] f2 (16 features); per-pair:
//   8 exp2 for even shifts, odd shifts via core_odd = core_even * R_base * c_h,
//   R_base = exp2(2*L*delta*dc) (1 exp2), c_h literal. dc = min(d, 5.3) bounds
//   all transcendental args (no inf/NaN from sentinels or self-pairs).

typedef float f2 __attribute__((ext_vector_type(2)));

constexpr int B = 16;
constexpr int N = 512;
constexpr int TARGET = 1008;
constexpr int SLOTS = 768;           // padded per-batch neighbor slots (>=512+4*63)

__device__ constexpr float SHF(int r) { return 0.9f + 0.26875f * r; }
constexpr float L16 = 23.083120654223414f;     // 16 * log2(e)
constexpr float LD  = 6.203588675822543f;      // L16 * 0.26875 (delta)
constexpr float LD2 = 12.407177351645086f;     // 2 * L16 * delta

__global__ __launch_bounds__(256) void sort_kernel(
    const int* __restrict__ species, const float* __restrict__ coords,
    float4* __restrict__ ws4, int* __restrict__ wsi)
{
    __shared__ int cnt[4];
    __shared__ int base[5];
    __shared__ int cur[4];
    const int b = blockIdx.x, tid = threadIdx.x;
    if (tid < 4) cnt[tid] = 0;
    __syncthreads();
    const int* sp = species + b * N;
    const float* cb = coords + b * N * 3;
    for (int a = tid; a < N; a += 256) atomicAdd(&cnt[sp[a]], 1);
    __syncthreads();
    if (tid == 0) {
        int o = 0;
        for (int s = 0; s < 4; ++s) {
            base[s] = o; cur[s] = o;
            o += ((cnt[s] + 63) >> 6) << 6;
        }
        base[4] = o;
    }
    __syncthreads();
    float4* w = ws4 + b * SLOTS;
    for (int t = tid; t < SLOTS; t += 256)
        w[t] = make_float4(2.0e4f, 2.0e4f, 2.0e4f, 0.0f);   // sentinel: d>>5.2
    __syncthreads();
    for (int a = tid; a < N; a += 256) {
        const int s = sp[a];
        const int p = atomicAdd(&cur[s], 1);
        w[p] = make_float4(cb[3 * a], cb[3 * a + 1], cb[3 * a + 2], (float)s);
    }
    if (tid < 5) wsi[b * 8 + tid] = base[tid];
}

__global__ __launch_bounds__(256) void aev_radial_kernel(
    const float* __restrict__ coordinates,   // (B, N, 3) original order
    const float4* __restrict__ ws4,          // sorted+padded neighbors
    const int* __restrict__ wsi,             // segment offsets (5 per batch)
    float* __restrict__ out)                 // (B, N, 1008)
{
    __shared__ float4 sc[SLOTS];

    const int tid  = threadIdx.x;
    const int bb   = blockIdx.x >> 7;
    const int tile = blockIdx.x & 127;

    const float4* wb = ws4 + bb * SLOTS;
    for (int t = tid; t < SLOTS; t += 256) sc[t] = wb[t];   // coalesced x4
    const int off0 = wsi[bb * 8 + 0];
    const int off1 = wsi[bb * 8 + 1];
    const int off2 = wsi[bb * 8 + 2];
    const int off3 = wsi[bb * 8 + 3];
    const int off4 = wsi[bb * 8 + 4];
    __syncthreads();

    const int wave = tid >> 6;
    const int lane = tid & 63;
    const int i    = tile * 4 + wave;            // original atom index

    const float xi = coordinates[(bb * N + i) * 3 + 0];
    const float yi = coordinates[(bb * N + i) * 3 + 1];
    const float zi = coordinates[(bb * N + i) * 3 + 2];

    const int offs[5] = {off0, off1, off2, off3, off4};
    float p[4];

    #pragma unroll
    for (int s = 0; s < 4; ++s) {
        f2 acc[8];
        #pragma unroll
        for (int k = 0; k < 8; ++k) acc[k] = f2{0.0f, 0.0f};

        const int it0 = offs[s] >> 6, it1 = offs[s + 1] >> 6;
        for (int it = it0; it < it1; ++it) {
            const float4 cj = sc[(it << 6) + lane];
            const float dx = xi - cj.x, dy = yi - cj.y, dz = zi - cj.z;
            const float sq = dx * dx + dy * dy + dz * dz;
            const float d  = __builtin_amdgcn_sqrtf(sq);
            const float dc = fminf(d, 5.3f);     // bounds all trans args

            float fc = 0.5f * __builtin_amdgcn_cosf(dc * (1.0f / 10.4f)) + 0.5f;
            fc = (d > 0.0f && d <= 5.2f) ? fc : 0.0f;
            const f2 fcv = {fc, fc};

            const float cd2 = L16 * sq;                          // L*d^2
            const float rb  = __builtin_amdgcn_exp2f(LD2 * dc);  // exp2(2Ld*dc)
            const f2 dcv = {dc, dc};
            const f2 cdv = {cd2, cd2};

            // even-shift exp args packed in pairs: arg_h = dc*A_h - (B_h + cd2)
            f2 ar[4];
            #pragma unroll
            for (int t = 0; t < 4; ++t) {
                const f2 Av = {2.0f * L16 * SHF(4 * t), 2.0f * L16 * SHF(4 * t + 2)};
                const f2 Bv = {L16 * SHF(4 * t) * SHF(4 * t),
                               L16 * SHF(4 * t + 2) * SHF(4 * t + 2)};
                ar[t] = dcv * Av - (Bv + cdv);
            }
            #pragma unroll
            for (int h = 0; h < 8; ++h) {
                const float arg = (h & 1) ? ar[h >> 1].y : ar[h >> 1].x;
                const float ce  = __builtin_amdgcn_exp2f(arg);       // r = 2h
                const float ch  = __builtin_exp2f(-(LD * (SHF(2 * h) + SHF(2 * h + 1)))); // literal
                const float co  = ce * (rb * ch);                    // r = 2h+1
                const f2 cp = {ce, co};
                acc[h] += cp * fcv;
            }
        }

        // scatter-reduce within each 16-lane group: feature = lane & 15
        int cnt = 8;
        #pragma unroll
        for (int m = 8; m >= 2; m >>= 1) {
            const int half = cnt >> 1;
            const bool up = (lane & m) != 0;
            #pragma unroll
            for (int k = 0; k < half; ++k) {
                const f2 keep = up ? acc[k + half] : acc[k];
                const f2 send = up ? acc[k] : acc[k + half];
                f2 r;
                r.x = __shfl_xor(send.x, m, 64);
                r.y = __shfl_xor(send.y, m, 64);
                acc[k] = keep + r;
            }
            cnt = half;
        }
        const bool hi = (lane & 1) != 0;
        const float snd = hi ? acc[0].x : acc[0].y;
        const float rcv = __shfl_xor(snd, 1, 64);
        p[s] = (hi ? acc[0].y : acc[0].x) + rcv;  // partial over own 16-group
    }

    // cross-group sums, then quadrant select -> coalesced store
    #pragma unroll
    for (int s = 0; s < 4; ++s) {
        const float t = p[s] + __shfl_xor(p[s], 16, 64);
        p[s] = t + __shfl_xor(t, 32, 64);
    }
    const int q = lane >> 4;
    float v = p[0];
    v = (q == 1) ? p[1] : v;
    v = (q == 2) ? p[2] : v;
    v = (q == 3) ? p[3] : v;

    float* row = out + (size_t)(bb * N + i) * TARGET;
    row[lane] = v;
    float4* row4 = reinterpret_cast<float4*>(row);
    const float4 z4 = make_float4(0.0f, 0.0f, 0.0f, 0.0f);
    #pragma unroll
    for (int idx = 16 + lane; idx < 252; idx += 64) row4[idx] = z4;
}

extern "C" void kernel_launch(void* const* d_in, const int* in_sizes, int n_in,
                              void* d_out, int out_size, void* d_ws, size_t ws_size,
                              hipStream_t stream) {
    const int*   species     = (const int*)d_in[0];
    const float* coordinates = (const float*)d_in[1];
    float*       out         = (float*)d_out;

    float4* ws4 = (float4*)d_ws;
    int*    wsi = (int*)((char*)d_ws + B * SLOTS * sizeof(float4));

    hipLaunchKernelGGL(sort_kernel, dim3(B), dim3(256), 0, stream,
                       species, coordinates, ws4, wsi);
    hipLaunchKernelGGL(aev_radial_kernel, dim3(B * 128), dim3(256), 0, stream,
                       coordinates, ws4, wsi, out);
}

// Round 4
// 80.946 us; speedup vs baseline: 1.4666x; 1.4666x over previous
//
#include <hip/hip_runtime.h>

// PureAEVComputer radial AEV on MI355X — R4: R2 skeleton (fixed 8-iter
// unrolled neighbor loop, species-masked f2 accumulators) + exp-chain:
// only 2 exp2-anchors per pair (r=3, r=11); other 14 Gaussians via
// multiplicative recurrence (constant second difference of exponents).
// Trans per pair-iter: sqrt + cos + rb + inv_rb + 2 anchors = 6 (was 18).

typedef float f2 __attribute__((ext_vector_type(2)));

constexpr int B = 16;
constexpr int N = 512;
constexpr int TARGET = 1008;

__device__ constexpr float SHF(int r) { return 0.9f + 0.26875f * r; }
constexpr float L16 = 23.083120654223414f;   // 16 * log2(e)
constexpr float DEL = 0.26875f;
constexpr float LD  = 6.203588675822543f;    // L16 * DEL
constexpr float LD2 = 12.407177351645086f;   // 2 * L16 * DEL

__global__ __launch_bounds__(256) void aev_radial_kernel(
    const int* __restrict__ species,       // (B, N)
    const float* __restrict__ coordinates, // (B, N, 3)
    float* __restrict__ out)               // (B, N, 1008)
{
    __shared__ float4 sc[N];   // xyz + species bits in .w

    const int tid  = threadIdx.x;
    const int bb   = blockIdx.x >> 7;
    const int tile = blockIdx.x & 127;

    const float* cb = coordinates + (size_t)bb * (N * 3);
    const int*   sb = species + bb * N;
    for (int a = tid; a < N; a += 256) {
        sc[a] = make_float4(cb[3 * a], cb[3 * a + 1], cb[3 * a + 2],
                            __int_as_float(sb[a]));
    }
    __syncthreads();

    const int wave = tid >> 6;
    const int lane = tid & 63;
    const int i    = tile * 4 + wave;

    const float4 ci = sc[i];

    f2 acc[32];
    #pragma unroll
    for (int k = 0; k < 32; ++k) acc[k] = f2{0.0f, 0.0f};

    // chain literals (all constant-folded)
    const float Q  = __builtin_exp2f(-2.0f * L16 * DEL * DEL);        // ratio of ratios
    const float KA = __builtin_exp2f(-LD * (SHF(3) + SHF(4)));        // t-seed A
    const float MA = __builtin_exp2f( LD * (SHF(2) + SHF(3)));        // u-seed A
    const float KB = __builtin_exp2f(-LD * (SHF(11) + SHF(12)));      // t-seed B
    const float MB = __builtin_exp2f( LD * (SHF(10) + SHF(11)));      // u-seed B

    #pragma unroll
    for (int jc = 0; jc < N; jc += 64) {     // compile-time 8 iterations
        const float4 cj = sc[jc + lane];     // ds_read_b128, conflict-free
        const float dx = ci.x - cj.x;
        const float dy = ci.y - cj.y;
        const float dz = ci.z - cj.z;
        const float sq = dx * dx + dy * dy + dz * dz;
        const float d  = __builtin_amdgcn_sqrtf(sq);
        const float dc = fminf(d, 5.3f);     // bounds all trans args
        const int spj  = __float_as_int(cj.w);

        float fc = 0.5f * __builtin_amdgcn_cosf(dc * (1.0f / 10.4f)) + 0.5f;
        fc = (d > 0.0f && d <= 5.2f) ? fc : 0.0f;

        const float Lsq = L16 * sq;
        const float rb  = __builtin_amdgcn_exp2f(LD2 * dc);   // exp2(+2Ld*dc)
        const float irb = __builtin_amdgcn_exp2f(-LD2 * dc);  // exp2(-2Ld*dc)

        float core[16];
        // ---- group A: anchor r=3, chain up to 7, down to 0 ----
        {
            const float argA = dc * (2.0f * L16 * SHF(3))
                             - (L16 * SHF(3) * SHF(3)) - Lsq;
            core[3] = __builtin_amdgcn_exp2f(argA);
            float t = rb * KA;
            core[4] = core[3] * t; t *= Q;
            core[5] = core[4] * t; t *= Q;
            core[6] = core[5] * t; t *= Q;
            core[7] = core[6] * t;
            float u = irb * MA;
            core[2] = core[3] * u; u *= Q;
            core[1] = core[2] * u; u *= Q;
            core[0] = core[1] * u;
        }
        // ---- group B: anchor r=11, chain up to 15, down to 8 ----
        {
            const float argB = dc * (2.0f * L16 * SHF(11))
                             - (L16 * SHF(11) * SHF(11)) - Lsq;
            core[11] = __builtin_amdgcn_exp2f(argB);
            float t = rb * KB;
            core[12] = core[11] * t; t *= Q;
            core[13] = core[12] * t; t *= Q;
            core[14] = core[13] * t; t *= Q;
            core[15] = core[14] * t;
            float u = irb * MB;
            core[10] = core[11] * u; u *= Q;
            core[9]  = core[10] * u; u *= Q;
            core[8]  = core[9]  * u;
        }

        const float f0 = (spj == 0) ? fc : 0.0f;
        const float f1 = (spj == 1) ? fc : 0.0f;
        const float f2v = (spj == 2) ? fc : 0.0f;
        const float f3 = (spj == 3) ? fc : 0.0f;
        const f2 fc0 = {f0, f0}, fc1 = {f1, f1}, fc2 = {f2v, f2v}, fc3 = {f3, f3};

        #pragma unroll
        for (int h = 0; h < 8; ++h) {
            const f2 cp = {core[2 * h], core[2 * h + 1]};
            acc[0 * 8 + h] += cp * fc0;      // v_pk_fma_f32 x4
            acc[1 * 8 + h] += cp * fc1;
            acc[2 * 8 + h] += cp * fc2;
            acc[3 * 8 + h] += cp * fc3;
        }
    }

    // Reduce-scatter: 5 f2 levels (m=32..2), then one float exchange (m=1).
    int cnt = 32;
    #pragma unroll
    for (int m = 32; m >= 2; m >>= 1) {
        const int half = cnt >> 1;
        const bool up = (lane & m) != 0;
        #pragma unroll
        for (int k = 0; k < half; ++k) {
            const f2 keep = up ? acc[k + half] : acc[k];
            const f2 send = up ? acc[k] : acc[k + half];
            f2 r;
            r.x = __shfl_xor(send.x, m, 64);
            r.y = __shfl_xor(send.y, m, 64);
            acc[k] = keep + r;
        }
        cnt = half;
    }
    const bool hi = (lane & 1) != 0;
    const float snd = hi ? acc[0].x : acc[0].y;
    const float rcv = __shfl_xor(snd, 1, 64);
    const float mine = (hi ? acc[0].y : acc[0].x) + rcv;

    float* row = out + (size_t)(bb * N + i) * TARGET;
    row[lane] = mine;
    float4* row4 = reinterpret_cast<float4*>(row);
    const float4 z4 = make_float4(0.0f, 0.0f, 0.0f, 0.0f);
    #pragma unroll
    for (int idx = 16 + lane; idx < 252; idx += 64) row4[idx] = z4;
}

extern "C" void kernel_launch(void* const* d_in, const int* in_sizes, int n_in,
                              void* d_out, int out_size, void* d_ws, size_t ws_size,
                              hipStream_t stream) {
    const int*   species     = (const int*)d_in[0];
    const float* coordinates = (const float*)d_in[1];
    float*       out         = (float*)d_out;

    dim3 grid(B * 128), block(256);   // 4 waves = 4 atoms per block
    hipLaunchKernelGGL(aev_radial_kernel, grid, block, 0, stream,
                       species, coordinates, out);
}